// Round 6
// baseline (1772.588 us; speedup 1.0000x reference)
//
#include <hip/hip_runtime.h>
#include <stdint.h>

typedef unsigned short u16;
typedef __attribute__((ext_vector_type(4))) float f32x4;
typedef __attribute__((ext_vector_type(8))) __bf16 bf16x8;
typedef __attribute__((address_space(3))) void lds_void;
typedef const __attribute__((address_space(1))) void gbl_void;

__device__ __forceinline__ u16 f2bf(float f) {
    uint32_t u = __float_as_uint(f);
    u += 0x7FFFu + ((u >> 16) & 1u);
    return (u16)(u >> 16);
}

// ---------------- x f32 -> bf16 ----------------
__global__ __launch_bounds__(256) void cvt_bf16_kernel(const float* __restrict__ in,
                                                       u16* __restrict__ out, int n4) {
    int i = blockIdx.x * 256 + threadIdx.x;
    if (i >= n4) return;
    float4 v = reinterpret_cast<const float4*>(in)[i];
    ushort4 o;
    o.x = f2bf(v.x); o.y = f2bf(v.y); o.z = f2bf(v.z); o.w = f2bf(v.w);
    reinterpret_cast<ushort4*>(out)[i] = o;
}

// ---------------- W [K][N] f32 -> Wt [N][K] bf16 (2048x2048) ----------------
__global__ __launch_bounds__(256) void transpose_w_kernel(const float* __restrict__ W,
                                                          u16* __restrict__ Wt) {
    __shared__ float tile[32][33];
    const int bx = blockIdx.x, by = blockIdx.y;
    const int tx = threadIdx.x;  // 0..31
    const int ty = threadIdx.y;  // 0..7
#pragma unroll
    for (int i = 0; i < 4; i++)
        tile[ty + i * 8][tx] = W[(size_t)(by * 32 + ty + i * 8) * 2048 + bx * 32 + tx];
    __syncthreads();
#pragma unroll
    for (int i = 0; i < 4; i++)
        Wt[(size_t)(bx * 32 + ty + i * 8) * 2048 + by * 32 + tx] = f2bf(tile[tx][ty + i * 8]);
}

// ---------------- GEMM 256x256, BK=64, 8 waves, 4-phase groups (T3+T4+T5) ----------------
// C[M][N] = A[M][K] * Bt[N][K]^T, bf16 in. LDS 128KB: 2 buffers x (A[256][64]+B[256][64]).
// Staging via global_load_lds (linear dest, pre-swizzled source chunk c ^= row&7);
// reads apply the same XOR -> conflict-free ds_read_b128.
// Group T = 4 phases on buffer T&1, each phase = one C-quadrant x K=64 (16 MFMA).
// ALL 4 half-tiles of tile T+1 are staged at phase 0 (max load->drain distance);
// group end: vmcnt(0) + barrier. NOTE: no min-waves launch bound — a VGPR cap
// below ~230 spills the 128-VGPR accumulator (round-5 lesson: 1.4 GB scratch).
template <bool F32OUT>
__global__ __launch_bounds__(512) void gemm256_kernel(const u16* __restrict__ A,
                                                      const u16* __restrict__ Bt,
                                                      void* __restrict__ Cout,
                                                      const float* __restrict__ bias,
                                                      int M, int N, int K) {
    __shared__ u16 lds[65536];  // 128 KiB
    const int tid = threadIdx.x;
    const int lane = tid & 63, w = tid >> 6;
    const int l15 = lane & 15, l4 = lane >> 4;
    const int wm = w >> 2, wn = w & 3;  // 2 x 4 wave grid; per-wave out 128x64
    const int bm = blockIdx.x, bn = blockIdx.y;

    f32x4 acc[8][4] = {};

    // staging geometry: one half-tile = 128 rows x 64 cols bf16 = 16KB = 2 loads/thread
    const int srow = tid >> 3;                 // 0..63 (row within 64-row sub-half)
    const int scs = (tid & 7) ^ (srow & 7);    // pre-swizzled source chunk
    const u16* gA = A + (size_t)(bm * 256 + srow) * K + scs * 8;
    const u16* gB = Bt + (size_t)(bn * 256 + srow) * K + scs * 8;
    const size_t rowK64 = (size_t)64 * K;
    u16* ldst = lds + tid * 8;

    // LDS u16 offsets: buf d: d*32768 | A: +0, B: +16384 | half H: +H*8192
#define STAGE_HALF(D, OP, H, T)                                                           \
    {                                                                                     \
        const u16* g_ = ((OP) ? gB : gA) + (size_t)(H) * 128 * K + (size_t)(T) * 64;      \
        u16* l_ = ldst + (D) * 32768 + (OP) * 16384 + (H) * 8192;                         \
        __builtin_amdgcn_global_load_lds((gbl_void*)g_, (lds_void*)l_, 16, 0, 0);         \
        __builtin_amdgcn_global_load_lds((gbl_void*)(g_ + rowK64), (lds_void*)(l_ + 4096),\
                                         16, 0, 0);                                       \
    }

    // phase Q of group on buffer D; Q==0 stages ALL of tile T1 into D^1 when ST.
    // GEND: group-end vmcnt(0) drain folded into the trailing barrier.
#define PHASE(D, Q, T1, ST, GEND)                                                         \
    {                                                                                     \
        if ((Q) == 0 && (ST)) {                                                           \
            STAGE_HALF((D) ^ 1, 0, 0, T1);                                                \
            STAGE_HALF((D) ^ 1, 0, 1, T1);                                                \
            STAGE_HALF((D) ^ 1, 1, 0, T1);                                                \
            STAGE_HALF((D) ^ 1, 1, 1, T1);                                                \
        }                                                                                 \
        const int mh = (Q) >> 1, nh = (Q) & 1;                                            \
        bf16x8 af[4][2], bfr[2][2];                                                       \
        const u16* ab = lds + (D) * 32768 + wm * 8192;                                    \
        const u16* bb = lds + (D) * 32768 + 16384 + (wn >> 1) * 8192;                     \
        _Pragma("unroll") for (int mm = 0; mm < 4; ++mm) {                                \
            const int ra = mh * 64 + mm * 16 + l15;                                       \
            _Pragma("unroll") for (int kk = 0; kk < 2; ++kk)                              \
                af[mm][kk] = *reinterpret_cast<const bf16x8*>(                            \
                    &ab[ra * 64 + (((kk * 4 + l4) ^ (ra & 7)) << 3)]);                    \
        }                                                                                 \
        _Pragma("unroll") for (int nn = 0; nn < 2; ++nn) {                                \
            const int rb = (wn & 1) * 64 + nh * 32 + nn * 16 + l15;                       \
            _Pragma("unroll") for (int kk = 0; kk < 2; ++kk)                              \
                bfr[nn][kk] = *reinterpret_cast<const bf16x8*>(                           \
                    &bb[rb * 64 + (((kk * 4 + l4) ^ (rb & 7)) << 3)]);                    \
        }                                                                                 \
        __builtin_amdgcn_s_barrier();                                                     \
        asm volatile("s_waitcnt lgkmcnt(0)" ::: "memory");                                \
        __builtin_amdgcn_sched_barrier(0);                                                \
        __builtin_amdgcn_s_setprio(1);                                                    \
        _Pragma("unroll") for (int kk = 0; kk < 2; ++kk)                                  \
            _Pragma("unroll") for (int mm = 0; mm < 4; ++mm)                              \
                _Pragma("unroll") for (int nn = 0; nn < 2; ++nn)                          \
                    acc[mh * 4 + mm][nh * 2 + nn] =                                       \
                        __builtin_amdgcn_mfma_f32_16x16x32_bf16(                          \
                            af[mm][kk], bfr[nn][kk], acc[mh * 4 + mm][nh * 2 + nn],       \
                            0, 0, 0);                                                     \
        __builtin_amdgcn_s_setprio(0);                                                    \
        if (GEND) {                                                                       \
            asm volatile("s_waitcnt vmcnt(0)" ::: "memory");                              \
            __builtin_amdgcn_sched_barrier(0);                                            \
        }                                                                                 \
        __builtin_amdgcn_s_barrier();                                                     \
        __builtin_amdgcn_sched_barrier(0);                                                \
    }

    const int nt = K >> 6;
    // prologue: tile 0 -> buf 0
    STAGE_HALF(0, 0, 0, 0);
    STAGE_HALF(0, 0, 1, 0);
    STAGE_HALF(0, 1, 0, 0);
    STAGE_HALF(0, 1, 1, 0);
    asm volatile("s_waitcnt vmcnt(0)" ::: "memory");
    __builtin_amdgcn_sched_barrier(0);
    __builtin_amdgcn_s_barrier();

    for (int T = 0; T < nt; ++T) {
        const bool st = (T + 1 < nt);
        if ((T & 1) == 0) {
            PHASE(0, 0, T + 1, st, false);
            PHASE(0, 1, T + 1, st, false);
            PHASE(0, 2, T + 1, st, false);
            PHASE(0, 3, T + 1, st, true);
        } else {
            PHASE(1, 0, T + 1, st, false);
            PHASE(1, 1, T + 1, st, false);
            PHASE(1, 2, T + 1, st, false);
            PHASE(1, 3, T + 1, st, true);
        }
    }
#undef PHASE
#undef STAGE_HALF

    const int rbase = bm * 256 + wm * 128;
    const int cbase = bn * 256 + wn * 64;
#pragma unroll
    for (int mi = 0; mi < 8; ++mi) {
#pragma unroll
        for (int ni = 0; ni < 4; ++ni) {
            const int c = cbase + ni * 16 + l15;
#pragma unroll
            for (int j = 0; j < 4; ++j) {
                const int rr = rbase + mi * 16 + l4 * 4 + j;
                if (F32OUT)
                    ((float*)Cout)[(size_t)rr * N + c] = acc[mi][ni][j] + bias[c];
                else
                    ((u16*)Cout)[(size_t)rr * N + c] = f2bf(acc[mi][ni][j]);
            }
        }
    }
}

// ---------------- causal flash attention (unchanged) ----------------
__global__ __launch_bounds__(256) void attn_kernel(const u16* __restrict__ qk,
                                                   const u16* __restrict__ vt,
                                                   u16* __restrict__ ctx) {
    __shared__ u16 Ks[64 * 128];     // [kv][dh], 16B chunk c stored at c ^ (kv&15)
    __shared__ u16 Vs[128 * 64];     // [dh][kv], 16B chunk c stored at c ^ (dh&7)
    __shared__ u16 Ps[4 * 16 * 64];  // per-wave [q][kv], chunk c at c ^ (q&7)
    const int tid = threadIdx.x, lane = tid & 63, w = tid >> 6;
    const int l15 = lane & 15, l4 = lane >> 4;
    const int flat = blockIdx.x;
    const int qt = 31 - (flat >> 6);
    const int bh = flat & 63;
    const int b = bh >> 4, h = bh & 15;
    const int qb = qt * 64;

    bf16x8 qf[4];
    {
        const size_t rowQ = (size_t)(b * 2048 + qb + w * 16 + l15) * 4096 + h * 128;
#pragma unroll
        for (int kk = 0; kk < 4; kk++)
            qf[kk] = *reinterpret_cast<const bf16x8*>(&qk[rowQ + kk * 32 + l4 * 8]);
    }

    const int krow_i = tid >> 4, kslot = tid & 15;
    const int vrow_i = tid >> 3, vslot = tid & 7;

    float m_r[4], l_r[4];
    f32x4 o[8] = {};
#pragma unroll
    for (int j = 0; j < 4; ++j) { m_r[j] = -1e30f; l_r[j] = 0.f; }

    for (int kt = 0; kt <= qt; ++kt) {
        const int kvb = kt * 64;
#pragma unroll
        for (int p = 0; p < 4; ++p) {
            const int rowk = p * 16 + krow_i;
            const int ck = kslot ^ (rowk & 15);
            __builtin_amdgcn_global_load_lds(
                (gbl_void*)(qk + (size_t)(b * 2048 + kvb + rowk) * 4096 + 2048 + h * 128 + ck * 8),
                (lds_void*)((char*)Ks + p * 4096 + w * 1024), 16, 0, 0);
        }
#pragma unroll
        for (int p = 0; p < 4; ++p) {
            const int rowv = p * 32 + vrow_i;
            const int cv = vslot ^ (rowv & 7);
            __builtin_amdgcn_global_load_lds(
                (gbl_void*)(vt + (size_t)(h * 128 + rowv) * 8192 + b * 2048 + kvb + cv * 8),
                (lds_void*)((char*)Vs + p * 4096 + w * 1024), 16, 0, 0);
        }
        __syncthreads();

        f32x4 s[4] = {};
#pragma unroll
        for (int cb = 0; cb < 4; ++cb) {
            const int krow = cb * 16 + l15;
#pragma unroll
            for (int kk = 0; kk < 4; ++kk) {
                bf16x8 kf = *reinterpret_cast<const bf16x8*>(
                    &Ks[krow * 128 + (((kk * 4 + l4) ^ (krow & 15)) << 3)]);
                s[cb] = __builtin_amdgcn_mfma_f32_16x16x32_bf16(qf[kk], kf, s[cb], 0, 0, 0);
            }
        }
        const float sc = 0.08838834764831845f;  // 1/sqrt(128)
#pragma unroll
        for (int cb = 0; cb < 4; ++cb) s[cb] *= sc;

        if (kt == qt) {
#pragma unroll
            for (int cb = 0; cb < 4; ++cb)
#pragma unroll
                for (int j = 0; j < 4; ++j) {
                    int lr = w * 16 + l4 * 4 + j, lc = cb * 16 + l15;
                    if (lc > lr) s[cb][j] = -1e30f;
                }
        }

#pragma unroll
        for (int j = 0; j < 4; ++j) {
            float tm = fmaxf(fmaxf(s[0][j], s[1][j]), fmaxf(s[2][j], s[3][j]));
#pragma unroll
            for (int msk = 1; msk < 16; msk <<= 1)
                tm = fmaxf(tm, __shfl_xor(tm, msk, 64));
            float mnew = fmaxf(m_r[j], tm);
            float alpha = __expf(m_r[j] - mnew);
            m_r[j] = mnew;
            float rs = 0.f;
#pragma unroll
            for (int cb = 0; cb < 4; ++cb) {
                float p = __expf(s[cb][j] - mnew);
                s[cb][j] = p;
                rs += p;
            }
#pragma unroll
            for (int msk = 1; msk < 16; msk <<= 1)
                rs += __shfl_xor(rs, msk, 64);
            l_r[j] = l_r[j] * alpha + rs;
#pragma unroll
            for (int d = 0; d < 8; ++d) o[d][j] *= alpha;
        }

#pragma unroll
        for (int cb = 0; cb < 4; ++cb)
#pragma unroll
            for (int j = 0; j < 4; ++j) {
                const int rr = l4 * 4 + j;
                const int e = cb * 16 + l15;
                Ps[w * 1024 + rr * 64 + (((e >> 3) ^ (rr & 7)) << 3) + (e & 7)] = f2bf(s[cb][j]);
            }

#pragma unroll
        for (int ks = 0; ks < 2; ++ks) {
            bf16x8 pf = *reinterpret_cast<const bf16x8*>(
                &Ps[w * 1024 + l15 * 64 + (((ks * 4 + l4) ^ (l15 & 7)) << 3)]);
#pragma unroll
            for (int d = 0; d < 8; ++d) {
                const int dr = d * 16 + l15;
                bf16x8 vf = *reinterpret_cast<const bf16x8*>(
                    &Vs[dr * 64 + (((ks * 4 + l4) ^ (dr & 7)) << 3)]);
                o[d] = __builtin_amdgcn_mfma_f32_16x16x32_bf16(pf, vf, o[d], 0, 0, 0);
            }
        }
        __syncthreads();
    }

#pragma unroll
    for (int j = 0; j < 4; ++j) {
        float inv = 1.0f / l_r[j];
        size_t row = (size_t)(b * 2048 + qb + w * 16 + l4 * 4 + j) * 2048 + h * 128;
#pragma unroll
        for (int d = 0; d < 8; ++d)
            ctx[row + d * 16 + l15] = f2bf(o[d][j] * inv);
    }
}

extern "C" void kernel_launch(void* const* d_in, const int* in_sizes, int n_in,
                              void* d_out, int out_size, void* d_ws, size_t ws_size,
                              hipStream_t stream) {
    const float* x  = (const float*)d_in[0];
    const float* Wq = (const float*)d_in[1];
    const float* Wk = (const float*)d_in[2];
    const float* Wv = (const float*)d_in[3];
    const float* Wo = (const float*)d_in[4];
    const float* bo = (const float*)d_in[5];
    float* out = (float*)d_out;

    char* ws = (char*)d_ws;
    u16* xb  = (u16*)(ws);                         // 8192x2048 bf16 (33.5MB); reused as ctx
    u16* wt  = (u16*)(ws + 33554432);              // WqT|WkT|WvT, 3x 2048x2048 bf16 (25.2MB)
    u16* wto = (u16*)(ws + 33554432 + 25165824);   // WoT 2048x2048 bf16 (8.4MB)
    u16* qk  = (u16*)(ws + 67108864);              // 8192x4096 bf16 (67.1MB)
    u16* vtb = (u16*)(ws + 134217728);             // 2048x8192 bf16 V^T (33.5MB)
    u16* wtv = wt + 2 * 2048 * 2048;
    u16* ctxb = xb;

    cvt_bf16_kernel<<<16384, 256, 0, stream>>>(x, xb, 4194304);
    dim3 tb(32, 8), tg(64, 64);
    transpose_w_kernel<<<tg, tb, 0, stream>>>(Wq, wt);
    transpose_w_kernel<<<tg, tb, 0, stream>>>(Wk, wt + 2048 * 2048);
    transpose_w_kernel<<<tg, tb, 0, stream>>>(Wv, wtv);
    transpose_w_kernel<<<tg, tb, 0, stream>>>(Wo, wto);

    // Q|K: [8192][4096] = xb @ [WqT|WkT]^T
    gemm256_kernel<false><<<dim3(32, 16), 512, 0, stream>>>(xb, wt, qk, nullptr, 8192, 4096, 2048);
    // V^T: [2048][8192] = WvT @ xb^T
    gemm256_kernel<false><<<dim3(8, 32), 512, 0, stream>>>(wtv, xb, vtb, nullptr, 2048, 8192, 2048);
    attn_kernel<<<2048, 256, 0, stream>>>(qk, vtb, ctxb);
    gemm256_kernel<true><<<dim3(32, 8), 512, 0, stream>>>(ctxb, wto, out, bo, 8192, 2048, 2048);
}

// Round 7
// 1772.151 us; speedup vs baseline: 1.0002x; 1.0002x over previous
//
#include <hip/hip_runtime.h>
#include <stdint.h>

typedef unsigned short u16;
typedef __attribute__((ext_vector_type(4))) float f32x4;
typedef __attribute__((ext_vector_type(8))) __bf16 bf16x8;
typedef __attribute__((address_space(3))) void lds_void;
typedef const __attribute__((address_space(1))) void gbl_void;

__device__ __forceinline__ u16 f2bf(float f) {
    uint32_t u = __float_as_uint(f);
    u += 0x7FFFu + ((u >> 16) & 1u);
    return (u16)(u >> 16);
}

// ---------------- x f32 -> bf16 ----------------
__global__ __launch_bounds__(256) void cvt_bf16_kernel(const float* __restrict__ in,
                                                       u16* __restrict__ out, int n4) {
    int i = blockIdx.x * 256 + threadIdx.x;
    if (i >= n4) return;
    float4 v = reinterpret_cast<const float4*>(in)[i];
    ushort4 o;
    o.x = f2bf(v.x); o.y = f2bf(v.y); o.z = f2bf(v.z); o.w = f2bf(v.w);
    reinterpret_cast<ushort4*>(out)[i] = o;
}

// ---------------- W [K][N] f32 -> Wt [N][K] bf16 (2048x2048) ----------------
__global__ __launch_bounds__(256) void transpose_w_kernel(const float* __restrict__ W,
                                                          u16* __restrict__ Wt) {
    __shared__ float tile[32][33];
    const int bx = blockIdx.x, by = blockIdx.y;
    const int tx = threadIdx.x;  // 0..31
    const int ty = threadIdx.y;  // 0..7
#pragma unroll
    for (int i = 0; i < 4; i++)
        tile[ty + i * 8][tx] = W[(size_t)(by * 32 + ty + i * 8) * 2048 + bx * 32 + tx];
    __syncthreads();
#pragma unroll
    for (int i = 0; i < 4; i++)
        Wt[(size_t)(bx * 32 + ty + i * 8) * 2048 + by * 32 + tx] = f2bf(tile[tx][ty + i * 8]);
}

// ---------------- GEMM 256x256, BK=64, 8 waves, 4-phase groups (T3+T4+T5) ----------------
// C[M][N] = A[M][K] * Bt[N][K]^T, bf16 in. LDS 128KB: 2 buffers x (A[256][64]+B[256][64]).
// Staging via global_load_lds (linear dest, pre-swizzled source chunk c ^= row&7);
// reads apply the same XOR -> conflict-free ds_read_b128 (PMC-verified: 0 conflicts).
// Group T = 4 phases on buffer T&1; ALL of tile T+1 staged at phase 0; group-end
// vmcnt(0)+barrier. amdgpu_waves_per_eu(2,2): LDS already caps us at 1 block/CU
// (2 waves/EU), so cap occupancy there and let the allocator use ~256 regs/wave —
// without this the backend budgets 128 and the 128-VGPR accumulator spills
// (rounds 5/6: WRITE_SIZE 1.4-1.9 GB of scratch traffic, MfmaUtil 7-9%).
template <bool F32OUT>
__global__ __launch_bounds__(512) __attribute__((amdgpu_waves_per_eu(2, 2)))
void gemm256_kernel(const u16* __restrict__ A,
                    const u16* __restrict__ Bt,
                    void* __restrict__ Cout,
                    const float* __restrict__ bias,
                    int M, int N, int K) {
    __shared__ u16 lds[65536];  // 128 KiB
    const int tid = threadIdx.x;
    const int lane = tid & 63, w = tid >> 6;
    const int l15 = lane & 15, l4 = lane >> 4;
    const int wm = w >> 2, wn = w & 3;  // 2 x 4 wave grid; per-wave out 128x64
    const int bm = blockIdx.x, bn = blockIdx.y;

    f32x4 acc[8][4] = {};

    // staging geometry: one half-tile = 128 rows x 64 cols bf16 = 16KB = 2 loads/thread
    const int srow = tid >> 3;                 // 0..63 (row within 64-row sub-half)
    const int scs = (tid & 7) ^ (srow & 7);    // pre-swizzled source chunk
    const u16* gA = A + (size_t)(bm * 256 + srow) * K + scs * 8;
    const u16* gB = Bt + (size_t)(bn * 256 + srow) * K + scs * 8;
    const size_t rowK64 = (size_t)64 * K;
    u16* ldst = lds + tid * 8;

    // LDS u16 offsets: buf d: d*32768 | A: +0, B: +16384 | half H: +H*8192
#define STAGE_HALF(D, OP, H, T)                                                           \
    {                                                                                     \
        const u16* g_ = ((OP) ? gB : gA) + (size_t)(H) * 128 * K + (size_t)(T) * 64;      \
        u16* l_ = ldst + (D) * 32768 + (OP) * 16384 + (H) * 8192;                         \
        __builtin_amdgcn_global_load_lds((gbl_void*)g_, (lds_void*)l_, 16, 0, 0);         \
        __builtin_amdgcn_global_load_lds((gbl_void*)(g_ + rowK64), (lds_void*)(l_ + 4096),\
                                         16, 0, 0);                                       \
    }

    // phase Q of group on buffer D; Q==0 stages ALL of tile T1 into D^1 when ST.
    // GEND: group-end vmcnt(0) drain folded into the trailing barrier.
#define PHASE(D, Q, T1, ST, GEND)                                                         \
    {                                                                                     \
        if ((Q) == 0 && (ST)) {                                                           \
            STAGE_HALF((D) ^ 1, 0, 0, T1);                                                \
            STAGE_HALF((D) ^ 1, 0, 1, T1);                                                \
            STAGE_HALF((D) ^ 1, 1, 0, T1);                                                \
            STAGE_HALF((D) ^ 1, 1, 1, T1);                                                \
        }                                                                                 \
        const int mh = (Q) >> 1, nh = (Q) & 1;                                            \
        bf16x8 af[4][2], bfr[2][2];                                                       \
        const u16* ab = lds + (D) * 32768 + wm * 8192;                                    \
        const u16* bb = lds + (D) * 32768 + 16384 + (wn >> 1) * 8192;                     \
        _Pragma("unroll") for (int mm = 0; mm < 4; ++mm) {                                \
            const int ra = mh * 64 + mm * 16 + l15;                                       \
            _Pragma("unroll") for (int kk = 0; kk < 2; ++kk)                              \
                af[mm][kk] = *reinterpret_cast<const bf16x8*>(                            \
                    &ab[ra * 64 + (((kk * 4 + l4) ^ (ra & 7)) << 3)]);                    \
        }                                                                                 \
        _Pragma("unroll") for (int nn = 0; nn < 2; ++nn) {                                \
            const int rb = (wn & 1) * 64 + nh * 32 + nn * 16 + l15;                       \
            _Pragma("unroll") for (int kk = 0; kk < 2; ++kk)                              \
                bfr[nn][kk] = *reinterpret_cast<const bf16x8*>(                           \
                    &bb[rb * 64 + (((kk * 4 + l4) ^ (rb & 7)) << 3)]);                    \
        }                                                                                 \
        __builtin_amdgcn_s_barrier();                                                     \
        asm volatile("s_waitcnt lgkmcnt(0)" ::: "memory");                                \
        __builtin_amdgcn_sched_barrier(0);                                                \
        __builtin_amdgcn_s_setprio(1);                                                    \
        _Pragma("unroll") for (int kk = 0; kk < 2; ++kk)                                  \
            _Pragma("unroll") for (int mm = 0; mm < 4; ++mm)                              \
                _Pragma("unroll") for (int nn = 0; nn < 2; ++nn)                          \
                    acc[mh * 4 + mm][nh * 2 + nn] =                                       \
                        __builtin_amdgcn_mfma_f32_16x16x32_bf16(                          \
                            af[mm][kk], bfr[nn][kk], acc[mh * 4 + mm][nh * 2 + nn],       \
                            0, 0, 0);                                                     \
        __builtin_amdgcn_s_setprio(0);                                                    \
        if (GEND) {                                                                       \
            asm volatile("s_waitcnt vmcnt(0)" ::: "memory");                              \
            __builtin_amdgcn_sched_barrier(0);                                            \
        }                                                                                 \
        __builtin_amdgcn_s_barrier();                                                     \
        __builtin_amdgcn_sched_barrier(0);                                                \
    }

    const int nt = K >> 6;
    // prologue: tile 0 -> buf 0
    STAGE_HALF(0, 0, 0, 0);
    STAGE_HALF(0, 0, 1, 0);
    STAGE_HALF(0, 1, 0, 0);
    STAGE_HALF(0, 1, 1, 0);
    asm volatile("s_waitcnt vmcnt(0)" ::: "memory");
    __builtin_amdgcn_sched_barrier(0);
    __builtin_amdgcn_s_barrier();

    for (int T = 0; T < nt; ++T) {
        const bool st = (T + 1 < nt);
        if ((T & 1) == 0) {
            PHASE(0, 0, T + 1, st, false);
            PHASE(0, 1, T + 1, st, false);
            PHASE(0, 2, T + 1, st, false);
            PHASE(0, 3, T + 1, st, true);
        } else {
            PHASE(1, 0, T + 1, st, false);
            PHASE(1, 1, T + 1, st, false);
            PHASE(1, 2, T + 1, st, false);
            PHASE(1, 3, T + 1, st, true);
        }
    }
#undef PHASE
#undef STAGE_HALF

    const int rbase = bm * 256 + wm * 128;
    const int cbase = bn * 256 + wn * 64;
#pragma unroll
    for (int mi = 0; mi < 8; ++mi) {
#pragma unroll
        for (int ni = 0; ni < 4; ++ni) {
            const int c = cbase + ni * 16 + l15;
#pragma unroll
            for (int j = 0; j < 4; ++j) {
                const int rr = rbase + mi * 16 + l4 * 4 + j;
                if (F32OUT)
                    ((float*)Cout)[(size_t)rr * N + c] = acc[mi][ni][j] + bias[c];
                else
                    ((u16*)Cout)[(size_t)rr * N + c] = f2bf(acc[mi][ni][j]);
            }
        }
    }
}

// ---------------- causal flash attention (unchanged) ----------------
__global__ __launch_bounds__(256) void attn_kernel(const u16* __restrict__ qk,
                                                   const u16* __restrict__ vt,
                                                   u16* __restrict__ ctx) {
    __shared__ u16 Ks[64 * 128];     // [kv][dh], 16B chunk c stored at c ^ (kv&15)
    __shared__ u16 Vs[128 * 64];     // [dh][kv], 16B chunk c stored at c ^ (dh&7)
    __shared__ u16 Ps[4 * 16 * 64];  // per-wave [q][kv], chunk c at c ^ (q&7)
    const int tid = threadIdx.x, lane = tid & 63, w = tid >> 6;
    const int l15 = lane & 15, l4 = lane >> 4;
    const int flat = blockIdx.x;
    const int qt = 31 - (flat >> 6);
    const int bh = flat & 63;
    const int b = bh >> 4, h = bh & 15;
    const int qb = qt * 64;

    bf16x8 qf[4];
    {
        const size_t rowQ = (size_t)(b * 2048 + qb + w * 16 + l15) * 4096 + h * 128;
#pragma unroll
        for (int kk = 0; kk < 4; kk++)
            qf[kk] = *reinterpret_cast<const bf16x8*>(&qk[rowQ + kk * 32 + l4 * 8]);
    }

    const int krow_i = tid >> 4, kslot = tid & 15;
    const int vrow_i = tid >> 3, vslot = tid & 7;

    float m_r[4], l_r[4];
    f32x4 o[8] = {};
#pragma unroll
    for (int j = 0; j < 4; ++j) { m_r[j] = -1e30f; l_r[j] = 0.f; }

    for (int kt = 0; kt <= qt; ++kt) {
        const int kvb = kt * 64;
#pragma unroll
        for (int p = 0; p < 4; ++p) {
            const int rowk = p * 16 + krow_i;
            const int ck = kslot ^ (rowk & 15);
            __builtin_amdgcn_global_load_lds(
                (gbl_void*)(qk + (size_t)(b * 2048 + kvb + rowk) * 4096 + 2048 + h * 128 + ck * 8),
                (lds_void*)((char*)Ks + p * 4096 + w * 1024), 16, 0, 0);
        }
#pragma unroll
        for (int p = 0; p < 4; ++p) {
            const int rowv = p * 32 + vrow_i;
            const int cv = vslot ^ (rowv & 7);
            __builtin_amdgcn_global_load_lds(
                (gbl_void*)(vt + (size_t)(h * 128 + rowv) * 8192 + b * 2048 + kvb + cv * 8),
                (lds_void*)((char*)Vs + p * 4096 + w * 1024), 16, 0, 0);
        }
        __syncthreads();

        f32x4 s[4] = {};
#pragma unroll
        for (int cb = 0; cb < 4; ++cb) {
            const int krow = cb * 16 + l15;
#pragma unroll
            for (int kk = 0; kk < 4; ++kk) {
                bf16x8 kf = *reinterpret_cast<const bf16x8*>(
                    &Ks[krow * 128 + (((kk * 4 + l4) ^ (krow & 15)) << 3)]);
                s[cb] = __builtin_amdgcn_mfma_f32_16x16x32_bf16(qf[kk], kf, s[cb], 0, 0, 0);
            }
        }
        const float sc = 0.08838834764831845f;  // 1/sqrt(128)
#pragma unroll
        for (int cb = 0; cb < 4; ++cb) s[cb] *= sc;

        if (kt == qt) {
#pragma unroll
            for (int cb = 0; cb < 4; ++cb)
#pragma unroll
                for (int j = 0; j < 4; ++j) {
                    int lr = w * 16 + l4 * 4 + j, lc = cb * 16 + l15;
                    if (lc > lr) s[cb][j] = -1e30f;
                }
        }

#pragma unroll
        for (int j = 0; j < 4; ++j) {
            float tm = fmaxf(fmaxf(s[0][j], s[1][j]), fmaxf(s[2][j], s[3][j]));
#pragma unroll
            for (int msk = 1; msk < 16; msk <<= 1)
                tm = fmaxf(tm, __shfl_xor(tm, msk, 64));
            float mnew = fmaxf(m_r[j], tm);
            float alpha = __expf(m_r[j] - mnew);
            m_r[j] = mnew;
            float rs = 0.f;
#pragma unroll
            for (int cb = 0; cb < 4; ++cb) {
                float p = __expf(s[cb][j] - mnew);
                s[cb][j] = p;
                rs += p;
            }
#pragma unroll
            for (int msk = 1; msk < 16; msk <<= 1)
                rs += __shfl_xor(rs, msk, 64);
            l_r[j] = l_r[j] * alpha + rs;
#pragma unroll
            for (int d = 0; d < 8; ++d) o[d][j] *= alpha;
        }

#pragma unroll
        for (int cb = 0; cb < 4; ++cb)
#pragma unroll
            for (int j = 0; j < 4; ++j) {
                const int rr = l4 * 4 + j;
                const int e = cb * 16 + l15;
                Ps[w * 1024 + rr * 64 + (((e >> 3) ^ (rr & 7)) << 3) + (e & 7)] = f2bf(s[cb][j]);
            }

#pragma unroll
        for (int ks = 0; ks < 2; ++ks) {
            bf16x8 pf = *reinterpret_cast<const bf16x8*>(
                &Ps[w * 1024 + l15 * 64 + (((ks * 4 + l4) ^ (l15 & 7)) << 3)]);
#pragma unroll
            for (int d = 0; d < 8; ++d) {
                const int dr = d * 16 + l15;
                bf16x8 vf = *reinterpret_cast<const bf16x8*>(
                    &Vs[dr * 64 + (((ks * 4 + l4) ^ (dr & 7)) << 3)]);
                o[d] = __builtin_amdgcn_mfma_f32_16x16x32_bf16(pf, vf, o[d], 0, 0, 0);
            }
        }
        __syncthreads();
    }

#pragma unroll
    for (int j = 0; j < 4; ++j) {
        float inv = 1.0f / l_r[j];
        size_t row = (size_t)(b * 2048 + qb + w * 16 + l4 * 4 + j) * 2048 + h * 128;
#pragma unroll
        for (int d = 0; d < 8; ++d)
            ctx[row + d * 16 + l15] = f2bf(o[d][j] * inv);
    }
}

extern "C" void kernel_launch(void* const* d_in, const int* in_sizes, int n_in,
                              void* d_out, int out_size, void* d_ws, size_t ws_size,
                              hipStream_t stream) {
    const float* x  = (const float*)d_in[0];
    const float* Wq = (const float*)d_in[1];
    const float* Wk = (const float*)d_in[2];
    const float* Wv = (const float*)d_in[3];
    const float* Wo = (const float*)d_in[4];
    const float* bo = (const float*)d_in[5];
    float* out = (float*)d_out;

    char* ws = (char*)d_ws;
    u16* xb  = (u16*)(ws);                         // 8192x2048 bf16 (33.5MB); reused as ctx
    u16* wt  = (u16*)(ws + 33554432);              // WqT|WkT|WvT, 3x 2048x2048 bf16 (25.2MB)
    u16* wto = (u16*)(ws + 33554432 + 25165824);   // WoT 2048x2048 bf16 (8.4MB)
    u16* qk  = (u16*)(ws + 67108864);              // 8192x4096 bf16 (67.1MB)
    u16* vtb = (u16*)(ws + 134217728);             // 2048x8192 bf16 V^T (33.5MB)
    u16* wtv = wt + 2 * 2048 * 2048;
    u16* ctxb = xb;

    cvt_bf16_kernel<<<16384, 256, 0, stream>>>(x, xb, 4194304);
    dim3 tb(32, 8), tg(64, 64);
    transpose_w_kernel<<<tg, tb, 0, stream>>>(Wq, wt);
    transpose_w_kernel<<<tg, tb, 0, stream>>>(Wk, wt + 2048 * 2048);
    transpose_w_kernel<<<tg, tb, 0, stream>>>(Wv, wtv);
    transpose_w_kernel<<<tg, tb, 0, stream>>>(Wo, wto);

    // Q|K: [8192][4096] = xb @ [WqT|WkT]^T
    gemm256_kernel<false><<<dim3(32, 16), 512, 0, stream>>>(xb, wt, qk, nullptr, 8192, 4096, 2048);
    // V^T: [2048][8192] = WvT @ xb^T
    gemm256_kernel<false><<<dim3(8, 32), 512, 0, stream>>>(wtv, xb, vtb, nullptr, 2048, 8192, 2048);
    attn_kernel<<<2048, 256, 0, stream>>>(qk, vtb, ctxb);
    gemm256_kernel<true><<<dim3(32, 8), 512, 0, stream>>>(ctxb, wto, out, bo, 8192, 2048, 2048);
}

// Round 9
// 1476.173 us; speedup vs baseline: 1.2008x; 1.2005x over previous
//
#include <hip/hip_runtime.h>
#include <stdint.h>

typedef unsigned short u16;
typedef __attribute__((ext_vector_type(4))) float f32x4;
typedef __attribute__((ext_vector_type(8))) __bf16 bf16x8;
typedef __attribute__((address_space(3))) void lds_void;
typedef const __attribute__((address_space(1))) void gbl_void;

__device__ __forceinline__ u16 f2bf(float f) {
    uint32_t u = __float_as_uint(f);
    u += 0x7FFFu + ((u >> 16) & 1u);
    return (u16)(u >> 16);
}

// ---------------- x f32 -> bf16 ----------------
__global__ __launch_bounds__(256) void cvt_bf16_kernel(const float* __restrict__ in,
                                                       u16* __restrict__ out, int n4) {
    int i = blockIdx.x * 256 + threadIdx.x;
    if (i >= n4) return;
    float4 v = reinterpret_cast<const float4*>(in)[i];
    ushort4 o;
    o.x = f2bf(v.x); o.y = f2bf(v.y); o.z = f2bf(v.z); o.w = f2bf(v.w);
    reinterpret_cast<ushort4*>(out)[i] = o;
}

// ---------------- W [K][N] f32 -> Wt [N][K] bf16 (2048x2048) ----------------
__global__ __launch_bounds__(256) void transpose_w_kernel(const float* __restrict__ W,
                                                          u16* __restrict__ Wt) {
    __shared__ float tile[32][33];
    const int bx = blockIdx.x, by = blockIdx.y;
    const int tx = threadIdx.x;  // 0..31
    const int ty = threadIdx.y;  // 0..7
#pragma unroll
    for (int i = 0; i < 4; i++)
        tile[ty + i * 8][tx] = W[(size_t)(by * 32 + ty + i * 8) * 2048 + bx * 32 + tx];
    __syncthreads();
#pragma unroll
    for (int i = 0; i < 4; i++)
        Wt[(size_t)(bx * 32 + ty + i * 8) * 2048 + by * 32 + tx] = f2bf(tile[tx][ty + i * 8]);
}

// ---------------- GEMM A: 256x256 tile, BK=64, 16 waves (1024 thr), 4-phase ----------------
// Per-wave output 64x64 -> acc = 64 VGPR; frags 32; total ~116 regs -> fits the
// 128-reg budget of a 1024-thread block BY CONSTRUCTION (r5-r8 lesson: the 8-wave
// 256^2 variant needs ~210 regs vs a 128 budget -> 1.9GB scratch spill, MfmaUtil 7%).
// LDS 128KB: 2 buf x (A[256][64] + B[256][64]), swizzled chunk c^=row&7 on the
// global source (linear gload_lds dest); reads apply the same XOR.
// Intrinsic MFMA only (r8 lesson: inline-asm MFMA lacks backend hazard handling).
template <bool F32OUT>
__global__ __launch_bounds__(1024) void gemm1024_kernel(const u16* __restrict__ A,
                                                        const u16* __restrict__ Bt,
                                                        void* __restrict__ Cout,
                                                        const float* __restrict__ bias,
                                                        int M, int N, int K) {
    __shared__ u16 lds[65536];  // 128 KiB
    const int tid = threadIdx.x;
    const int lane = tid & 63, w = tid >> 6;   // 16 waves
    const int l15 = lane & 15, l4 = lane >> 4;
    const int wm2 = w >> 2, wn2 = w & 3;       // 4x4 wave grid, 64x64 out each
    const int bm = blockIdx.x, bn = blockIdx.y;

    f32x4 acc[4][4] = {};

    // staging: one half-tile = 128 rows x 64 cols = 16KB = 1024 thr x 16B (1 load)
    const int srow = tid >> 3;               // 0..127
    const int scs = (tid & 7) ^ (srow & 7);  // pre-swizzled source chunk
    const u16* gA = A + (size_t)(bm * 256 + srow) * K + scs * 8;
    const u16* gB = Bt + (size_t)(bn * 256 + srow) * K + scs * 8;
    const size_t rowK128 = (size_t)128 * K;
    u16* ldst = lds + tid * 8;

    // LDS u16 offsets: buf D: D*32768 | A: +0, B: +16384 | half H: +H*8192
#define STAGE_HALF(D, OP, H, T)                                                     \
    __builtin_amdgcn_global_load_lds(                                               \
        (gbl_void*)(((OP) ? gB : gA) + (size_t)(H) * rowK128 + (size_t)(T) * 64),   \
        (lds_void*)(ldst + (D) * 32768 + (OP) * 16384 + (H) * 8192), 16, 0, 0);

#define PHASE(D, Q, T1, ST, GEND)                                                   \
    {                                                                               \
        if ((Q) == 0 && (ST)) {                                                     \
            STAGE_HALF((D) ^ 1, 0, 0, T1);                                          \
            STAGE_HALF((D) ^ 1, 0, 1, T1);                                          \
            STAGE_HALF((D) ^ 1, 1, 0, T1);                                          \
            STAGE_HALF((D) ^ 1, 1, 1, T1);                                          \
        }                                                                           \
        const int mh = (Q) >> 1, nh = (Q) & 1;                                      \
        bf16x8 af[2][2], bfr[2][2];                                                 \
        _Pragma("unroll") for (int mm = 0; mm < 2; ++mm) {                          \
            const int ra = wm2 * 64 + mh * 32 + mm * 16 + l15;                      \
            _Pragma("unroll") for (int kk = 0; kk < 2; ++kk)                        \
                af[mm][kk] = *reinterpret_cast<const bf16x8*>(                      \
                    &lds[(D) * 32768 + ra * 64 + (((kk * 4 + l4) ^ (ra & 7)) << 3)]);\
        }                                                                           \
        _Pragma("unroll") for (int nn = 0; nn < 2; ++nn) {                          \
            const int rb = wn2 * 64 + nh * 32 + nn * 16 + l15;                      \
            _Pragma("unroll") for (int kk = 0; kk < 2; ++kk)                        \
                bfr[nn][kk] = *reinterpret_cast<const bf16x8*>(                     \
                    &lds[(D) * 32768 + 16384 + rb * 64 +                            \
                         (((kk * 4 + l4) ^ (rb & 7)) << 3)]);                       \
        }                                                                           \
        __builtin_amdgcn_s_barrier();                                               \
        asm volatile("s_waitcnt lgkmcnt(0)" ::: "memory");                          \
        __builtin_amdgcn_sched_barrier(0);                                          \
        __builtin_amdgcn_s_setprio(1);                                              \
        _Pragma("unroll") for (int kk = 0; kk < 2; ++kk)                            \
            _Pragma("unroll") for (int mm = 0; mm < 2; ++mm)                        \
                _Pragma("unroll") for (int nn = 0; nn < 2; ++nn)                    \
                    acc[mh * 2 + mm][nh * 2 + nn] =                                 \
                        __builtin_amdgcn_mfma_f32_16x16x32_bf16(                    \
                            af[mm][kk], bfr[nn][kk], acc[mh * 2 + mm][nh * 2 + nn], \
                            0, 0, 0);                                               \
        __builtin_amdgcn_s_setprio(0);                                              \
        if (GEND) {                                                                 \
            asm volatile("s_waitcnt vmcnt(0)" ::: "memory");                        \
            __builtin_amdgcn_sched_barrier(0);                                      \
        }                                                                           \
        __builtin_amdgcn_s_barrier();                                               \
        __builtin_amdgcn_sched_barrier(0);                                          \
    }

    const int nt = K >> 6;
    STAGE_HALF(0, 0, 0, 0);
    STAGE_HALF(0, 0, 1, 0);
    STAGE_HALF(0, 1, 0, 0);
    STAGE_HALF(0, 1, 1, 0);
    asm volatile("s_waitcnt vmcnt(0)" ::: "memory");
    __builtin_amdgcn_sched_barrier(0);
    __builtin_amdgcn_s_barrier();

    for (int T = 0; T < nt; ++T) {
        const bool st = (T + 1 < nt);
        if ((T & 1) == 0) {
            PHASE(0, 0, T + 1, st, false);
            PHASE(0, 1, T + 1, st, false);
            PHASE(0, 2, T + 1, st, false);
            PHASE(0, 3, T + 1, st, true);
        } else {
            PHASE(1, 0, T + 1, st, false);
            PHASE(1, 1, T + 1, st, false);
            PHASE(1, 2, T + 1, st, false);
            PHASE(1, 3, T + 1, st, true);
        }
    }
#undef PHASE
#undef STAGE_HALF

    const int rbase = bm * 256 + wm2 * 64;
    const int cbase = bn * 256 + wn2 * 64;
#pragma unroll
    for (int mi = 0; mi < 4; ++mi) {
#pragma unroll
        for (int ni = 0; ni < 4; ++ni) {
            const int c = cbase + ni * 16 + l15;
#pragma unroll
            for (int j = 0; j < 4; ++j) {
                const int rr = rbase + mi * 16 + l4 * 4 + j;
                if (F32OUT)
                    ((float*)Cout)[(size_t)rr * N + c] = acc[mi][ni][j] + bias[c];
                else
                    ((u16*)Cout)[(size_t)rr * N + c] = f2bf(acc[mi][ni][j]);
            }
        }
    }
}

// ---------------- GEMM B: r4-proven 128x128, 3-slot ring (natural block order) ----------------
template <bool F32OUT>
__global__ __launch_bounds__(256) void gemm_bt_kernel(const u16* __restrict__ A,
                                                      const u16* __restrict__ Bt,
                                                      void* __restrict__ Cout,
                                                      const float* __restrict__ bias,
                                                      int M, int N, int K) {
    __shared__ u16 As[3 * 4096];
    __shared__ u16 Bs[3 * 4096];
    const int tid = threadIdx.x;
    const int lane = tid & 63, wave = tid >> 6;
    const int l15 = lane & 15, l4 = lane >> 4;
    const int wm = wave >> 1, wn = wave & 1;
    const int bm = blockIdx.x, bn = blockIdx.y;

    f32x4 acc[4][4] = {};

    const int r0 = tid >> 2;
    const int r1 = r0 + 64;
    const int c0 = (tid & 3) * 8;
    const u16* ga0 = A + (size_t)(bm * 128 + r0) * K + c0;
    const u16* ga1 = A + (size_t)(bm * 128 + r1) * K + c0;
    const u16* gb0 = Bt + (size_t)(bn * 128 + r0) * K + c0;
    const u16* gb1 = Bt + (size_t)(bn * 128 + r1) * K + c0;
    const int woff = wave * 1024;

#define STAGE_TILE(T, SLOT)                                                              \
    {                                                                                    \
        const int kb_ = (T) << 5;                                                        \
        const int sb_ = (SLOT) * 8192;                                                   \
        __builtin_amdgcn_global_load_lds((gbl_void*)(ga0 + kb_),                         \
                                         (lds_void*)((char*)As + sb_ + woff), 16, 0, 0); \
        __builtin_amdgcn_global_load_lds((gbl_void*)(ga1 + kb_),                         \
                                         (lds_void*)((char*)As + sb_ + 4096 + woff), 16, 0, 0); \
        __builtin_amdgcn_global_load_lds((gbl_void*)(gb0 + kb_),                         \
                                         (lds_void*)((char*)Bs + sb_ + woff), 16, 0, 0); \
        __builtin_amdgcn_global_load_lds((gbl_void*)(gb1 + kb_),                         \
                                         (lds_void*)((char*)Bs + sb_ + 4096 + woff), 16, 0, 0); \
    }

    const int nt = K >> 5;
    STAGE_TILE(0, 0);
    STAGE_TILE(1, 1);

    int cs = 0, ps = 2;
    for (int t = 0; t < nt; ++t) {
        if (t + 2 < nt) {
            STAGE_TILE(t + 2, ps);
            asm volatile("s_waitcnt vmcnt(8)" ::: "memory");
        } else if (t + 2 == nt) {
            asm volatile("s_waitcnt vmcnt(4)" ::: "memory");
        } else {
            asm volatile("s_waitcnt vmcnt(0)" ::: "memory");
        }
        __builtin_amdgcn_s_barrier();
        __builtin_amdgcn_sched_barrier(0);

        const u16* as = As + cs * 4096;
        const u16* bs = Bs + cs * 4096;
        bf16x8 af[4], bfr[4];
#pragma unroll
        for (int m = 0; m < 4; ++m)
            af[m] = *reinterpret_cast<const bf16x8*>(&as[(wm * 64 + m * 16 + l15) * 32 + l4 * 8]);
#pragma unroll
        for (int n = 0; n < 4; ++n)
            bfr[n] = *reinterpret_cast<const bf16x8*>(&bs[(wn * 64 + n * 16 + l15) * 32 + l4 * 8]);
#pragma unroll
        for (int m = 0; m < 4; ++m)
#pragma unroll
            for (int n = 0; n < 4; ++n)
                acc[m][n] = __builtin_amdgcn_mfma_f32_16x16x32_bf16(af[m], bfr[n], acc[m][n], 0, 0, 0);

        __builtin_amdgcn_s_barrier();
        __builtin_amdgcn_sched_barrier(0);
        cs = (cs == 2) ? 0 : cs + 1;
        ps = (ps == 2) ? 0 : ps + 1;
    }
#undef STAGE_TILE

    const int rbase = bm * 128 + wm * 64;
    const int cbase = bn * 128 + wn * 64;
#pragma unroll
    for (int m = 0; m < 4; ++m) {
#pragma unroll
        for (int n = 0; n < 4; ++n) {
            const int c = cbase + n * 16 + l15;
#pragma unroll
            for (int j = 0; j < 4; ++j) {
                const int rr = rbase + m * 16 + l4 * 4 + j;
                if (F32OUT)
                    ((float*)Cout)[(size_t)rr * N + c] = acc[m][n][j] + bias[c];
                else
                    ((u16*)Cout)[(size_t)rr * N + c] = f2bf(acc[m][n][j]);
            }
        }
    }
}

// ---------------- causal flash attention (unchanged) ----------------
__global__ __launch_bounds__(256) void attn_kernel(const u16* __restrict__ qk,
                                                   const u16* __restrict__ vt,
                                                   u16* __restrict__ ctx) {
    __shared__ u16 Ks[64 * 128];     // [kv][dh], 16B chunk c stored at c ^ (kv&15)
    __shared__ u16 Vs[128 * 64];     // [dh][kv], 16B chunk c stored at c ^ (dh&7)
    __shared__ u16 Ps[4 * 16 * 64];  // per-wave [q][kv], chunk c at c ^ (q&7)
    const int tid = threadIdx.x, lane = tid & 63, w = tid >> 6;
    const int l15 = lane & 15, l4 = lane >> 4;
    const int flat = blockIdx.x;
    const int qt = 31 - (flat >> 6);
    const int bh = flat & 63;
    const int b = bh >> 4, h = bh & 15;
    const int qb = qt * 64;

    bf16x8 qf[4];
    {
        const size_t rowQ = (size_t)(b * 2048 + qb + w * 16 + l15) * 4096 + h * 128;
#pragma unroll
        for (int kk = 0; kk < 4; kk++)
            qf[kk] = *reinterpret_cast<const bf16x8*>(&qk[rowQ + kk * 32 + l4 * 8]);
    }

    const int krow_i = tid >> 4, kslot = tid & 15;
    const int vrow_i = tid >> 3, vslot = tid & 7;

    float m_r[4], l_r[4];
    f32x4 o[8] = {};
#pragma unroll
    for (int j = 0; j < 4; ++j) { m_r[j] = -1e30f; l_r[j] = 0.f; }

    for (int kt = 0; kt <= qt; ++kt) {
        const int kvb = kt * 64;
#pragma unroll
        for (int p = 0; p < 4; ++p) {
            const int rowk = p * 16 + krow_i;
            const int ck = kslot ^ (rowk & 15);
            __builtin_amdgcn_global_load_lds(
                (gbl_void*)(qk + (size_t)(b * 2048 + kvb + rowk) * 4096 + 2048 + h * 128 + ck * 8),
                (lds_void*)((char*)Ks + p * 4096 + w * 1024), 16, 0, 0);
        }
#pragma unroll
        for (int p = 0; p < 4; ++p) {
            const int rowv = p * 32 + vrow_i;
            const int cv = vslot ^ (rowv & 7);
            __builtin_amdgcn_global_load_lds(
                (gbl_void*)(vt + (size_t)(h * 128 + rowv) * 8192 + b * 2048 + kvb + cv * 8),
                (lds_void*)((char*)Vs + p * 4096 + w * 1024), 16, 0, 0);
        }
        __syncthreads();

        f32x4 s[4] = {};
#pragma unroll
        for (int cb = 0; cb < 4; ++cb) {
            const int krow = cb * 16 + l15;
#pragma unroll
            for (int kk = 0; kk < 4; ++kk) {
                bf16x8 kf = *reinterpret_cast<const bf16x8*>(
                    &Ks[krow * 128 + (((kk * 4 + l4) ^ (krow & 15)) << 3)]);
                s[cb] = __builtin_amdgcn_mfma_f32_16x16x32_bf16(qf[kk], kf, s[cb], 0, 0, 0);
            }
        }
        const float sc = 0.08838834764831845f;  // 1/sqrt(128)
#pragma unroll
        for (int cb = 0; cb < 4; ++cb) s[cb] *= sc;

        if (kt == qt) {
#pragma unroll
            for (int cb = 0; cb < 4; ++cb)
#pragma unroll
                for (int j = 0; j < 4; ++j) {
                    int lr = w * 16 + l4 * 4 + j, lc = cb * 16 + l15;
                    if (lc > lr) s[cb][j] = -1e30f;
                }
        }

#pragma unroll
        for (int j = 0; j < 4; ++j) {
            float tm = fmaxf(fmaxf(s[0][j], s[1][j]), fmaxf(s[2][j], s[3][j]));
#pragma unroll
            for (int msk = 1; msk < 16; msk <<= 1)
                tm = fmaxf(tm, __shfl_xor(tm, msk, 64));
            float mnew = fmaxf(m_r[j], tm);
            float alpha = __expf(m_r[j] - mnew);
            m_r[j] = mnew;
            float rs = 0.f;
#pragma unroll
            for (int cb = 0; cb < 4; ++cb) {
                float p = __expf(s[cb][j] - mnew);
                s[cb][j] = p;
                rs += p;
            }
#pragma unroll
            for (int msk = 1; msk < 16; msk <<= 1)
                rs += __shfl_xor(rs, msk, 64);
            l_r[j] = l_r[j] * alpha + rs;
#pragma unroll
            for (int d = 0; d < 8; ++d) o[d][j] *= alpha;
        }

#pragma unroll
        for (int cb = 0; cb < 4; ++cb)
#pragma unroll
            for (int j = 0; j < 4; ++j) {
                const int rr = l4 * 4 + j;
                const int e = cb * 16 + l15;
                Ps[w * 1024 + rr * 64 + (((e >> 3) ^ (rr & 7)) << 3) + (e & 7)] = f2bf(s[cb][j]);
            }

#pragma unroll
        for (int ks = 0; ks < 2; ++ks) {
            bf16x8 pf = *reinterpret_cast<const bf16x8*>(
                &Ps[w * 1024 + l15 * 64 + (((ks * 4 + l4) ^ (l15 & 7)) << 3)]);
#pragma unroll
            for (int d = 0; d < 8; ++d) {
                const int dr = d * 16 + l15;
                bf16x8 vf = *reinterpret_cast<const bf16x8*>(
                    &Vs[dr * 64 + (((ks * 4 + l4) ^ (dr & 7)) << 3)]);
                o[d] = __builtin_amdgcn_mfma_f32_16x16x32_bf16(pf, vf, o[d], 0, 0, 0);
            }
        }
        __syncthreads();
    }

#pragma unroll
    for (int j = 0; j < 4; ++j) {
        float inv = 1.0f / l_r[j];
        size_t row = (size_t)(b * 2048 + qb + w * 16 + l4 * 4 + j) * 2048 + h * 128;
#pragma unroll
        for (int d = 0; d < 8; ++d)
            ctx[row + d * 16 + l15] = f2bf(o[d][j] * inv);
    }
}

extern "C" void kernel_launch(void* const* d_in, const int* in_sizes, int n_in,
                              void* d_out, int out_size, void* d_ws, size_t ws_size,
                              hipStream_t stream) {
    const float* x  = (const float*)d_in[0];
    const float* Wq = (const float*)d_in[1];
    const float* Wk = (const float*)d_in[2];
    const float* Wv = (const float*)d_in[3];
    const float* Wo = (const float*)d_in[4];
    const float* bo = (const float*)d_in[5];
    float* out = (float*)d_out;

    char* ws = (char*)d_ws;
    u16* xb  = (u16*)(ws);                         // 8192x2048 bf16 (33.5MB); reused as ctx
    u16* wt  = (u16*)(ws + 33554432);              // WqT|WkT|WvT, 3x 2048x2048 bf16 (25.2MB)
    u16* wto = (u16*)(ws + 33554432 + 25165824);   // WoT 2048x2048 bf16 (8.4MB)
    u16* qk  = (u16*)(ws + 67108864);              // 8192x4096 bf16 (67.1MB)
    u16* vtb = (u16*)(ws + 134217728);             // 2048x8192 bf16 V^T (33.5MB)
    u16* wtv = wt + 2 * 2048 * 2048;
    u16* ctxb = xb;

    cvt_bf16_kernel<<<16384, 256, 0, stream>>>(x, xb, 4194304);
    dim3 tb(32, 8), tg(64, 64);
    transpose_w_kernel<<<tg, tb, 0, stream>>>(Wq, wt);
    transpose_w_kernel<<<tg, tb, 0, stream>>>(Wk, wt + 2048 * 2048);
    transpose_w_kernel<<<tg, tb, 0, stream>>>(Wv, wtv);
    transpose_w_kernel<<<tg, tb, 0, stream>>>(Wo, wto);

    // Q|K: [8192][4096] = xb @ [WqT|WkT]^T  (new 16-wave 256^2 kernel)
    gemm1024_kernel<false><<<dim3(32, 16), 1024, 0, stream>>>(xb, wt, qk, nullptr, 8192, 4096, 2048);
    // V^T: [2048][8192] = WvT @ xb^T  (proven ring kernel)
    gemm_bt_kernel<false><<<dim3(16, 64), 256, 0, stream>>>(wtv, xb, vtb, nullptr, 2048, 8192, 2048);
    attn_kernel<<<2048, 256, 0, stream>>>(qk, vtb, ctxb);
    gemm_bt_kernel<true><<<dim3(64, 16), 256, 0, stream>>>(ctxb, wto, out, bo, 8192, 2048, 2048);
}

// Round 12
// 599.465 us; speedup vs baseline: 2.9570x; 2.4625x over previous
//
#include <hip/hip_runtime.h>
#include <stdint.h>

typedef unsigned short u16;
typedef __attribute__((ext_vector_type(4))) float f32x4;
typedef __attribute__((ext_vector_type(8))) __bf16 bf16x8;
typedef __attribute__((address_space(3))) void lds_void;
typedef const __attribute__((address_space(1))) void gbl_void;

__device__ __forceinline__ u16 f2bf(float f) {
    uint32_t u = __float_as_uint(f);
    u += 0x7FFFu + ((u >> 16) & 1u);
    return (u16)(u >> 16);
}

// ---------------- x f32 -> bf16 ----------------
__global__ __launch_bounds__(256) void cvt_bf16_kernel(const float* __restrict__ in,
                                                       u16* __restrict__ out, int n4) {
    int i = blockIdx.x * 256 + threadIdx.x;
    if (i >= n4) return;
    float4 v = reinterpret_cast<const float4*>(in)[i];
    ushort4 o;
    o.x = f2bf(v.x); o.y = f2bf(v.y); o.z = f2bf(v.z); o.w = f2bf(v.w);
    reinterpret_cast<ushort4*>(out)[i] = o;
}

// ---------------- W [K][N] f32 -> Wt [N][K] bf16 (2048x2048) ----------------
__global__ __launch_bounds__(256) void transpose_w_kernel(const float* __restrict__ W,
                                                          u16* __restrict__ Wt) {
    __shared__ float tile[32][33];
    const int bx = blockIdx.x, by = blockIdx.y;
    const int tx = threadIdx.x;  // 0..31
    const int ty = threadIdx.y;  // 0..7
#pragma unroll
    for (int i = 0; i < 4; i++)
        tile[ty + i * 8][tx] = W[(size_t)(by * 32 + ty + i * 8) * 2048 + bx * 32 + tx];
    __syncthreads();
#pragma unroll
    for (int i = 0; i < 4; i++)
        Wt[(size_t)(bx * 32 + ty + i * 8) * 2048 + by * 32 + tx] = f2bf(tile[tx][ty + i * 8]);
}

// ---------------- GEMM (r4-proven): 128x128, 4 waves, BK=32, 3-slot LDS ring ----------------
// Prefetch distance 2, counted vmcnt(8), raw barriers, XCD-bijective swizzle (m204).
// PROVEN at 716 TF (r4). Do NOT: >256-thr blocks (VGPR budget 128/64 -> acc spills,
// r5-r9), 2-buffer distance-2 (self-race, r10), inline-asm MFMA (hazards, r8).
template <bool F32OUT>
__global__ __launch_bounds__(256) void gemm_bt_kernel(const u16* __restrict__ A,
                                                      const u16* __restrict__ Bt,
                                                      void* __restrict__ Cout,
                                                      const float* __restrict__ bias,
                                                      int M, int N, int K) {
    __shared__ u16 As[3 * 4096];  // 3 slots x [128][32]
    __shared__ u16 Bs[3 * 4096];
    const int tid = threadIdx.x;
    const int lane = tid & 63, wave = tid >> 6;
    const int l15 = lane & 15, l4 = lane >> 4;
    const int wm = wave >> 1, wn = wave & 1;

    const int gx = gridDim.x;
    const int nwg = gx * gridDim.y;
    const int flat0 = blockIdx.y * gx + blockIdx.x;
    const int q = nwg >> 3, r = nwg & 7;
    const int xcd = flat0 & 7, idx = flat0 >> 3;
    const int wgid = (xcd < r ? xcd * (q + 1) : r * (q + 1) + (xcd - r) * q) + idx;
    const int bm = wgid % gx, bn = wgid / gx;

    f32x4 acc[4][4] = {};

    const int r0 = tid >> 2;
    const int r1 = r0 + 64;
    const int c0 = (tid & 3) * 8;
    const u16* ga0 = A + (size_t)(bm * 128 + r0) * K + c0;
    const u16* ga1 = A + (size_t)(bm * 128 + r1) * K + c0;
    const u16* gb0 = Bt + (size_t)(bn * 128 + r0) * K + c0;
    const u16* gb1 = Bt + (size_t)(bn * 128 + r1) * K + c0;
    const int woff = wave * 1024;

#define STAGE_TILE(T, SLOT)                                                              \
    {                                                                                    \
        const int kb_ = (T) << 5;                                                        \
        const int sb_ = (SLOT) * 8192;                                                   \
        __builtin_amdgcn_global_load_lds((gbl_void*)(ga0 + kb_),                         \
                                         (lds_void*)((char*)As + sb_ + woff), 16, 0, 0); \
        __builtin_amdgcn_global_load_lds((gbl_void*)(ga1 + kb_),                         \
                                         (lds_void*)((char*)As + sb_ + 4096 + woff), 16, 0, 0); \
        __builtin_amdgcn_global_load_lds((gbl_void*)(gb0 + kb_),                         \
                                         (lds_void*)((char*)Bs + sb_ + woff), 16, 0, 0); \
        __builtin_amdgcn_global_load_lds((gbl_void*)(gb1 + kb_),                         \
                                         (lds_void*)((char*)Bs + sb_ + 4096 + woff), 16, 0, 0); \
    }

    const int nt = K >> 5;
    STAGE_TILE(0, 0);
    STAGE_TILE(1, 1);

    int cs = 0, ps = 2;
    for (int t = 0; t < nt; ++t) {
        if (t + 2 < nt) {
            STAGE_TILE(t + 2, ps);
            asm volatile("s_waitcnt vmcnt(8)" ::: "memory");
        } else if (t + 2 == nt) {
            asm volatile("s_waitcnt vmcnt(4)" ::: "memory");
        } else {
            asm volatile("s_waitcnt vmcnt(0)" ::: "memory");
        }
        __builtin_amdgcn_s_barrier();
        __builtin_amdgcn_sched_barrier(0);

        const u16* as = As + cs * 4096;
        const u16* bs = Bs + cs * 4096;
        bf16x8 af[4], bfr[4];
#pragma unroll
        for (int m = 0; m < 4; ++m)
            af[m] = *reinterpret_cast<const bf16x8*>(&as[(wm * 64 + m * 16 + l15) * 32 + l4 * 8]);
#pragma unroll
        for (int n = 0; n < 4; ++n)
            bfr[n] = *reinterpret_cast<const bf16x8*>(&bs[(wn * 64 + n * 16 + l15) * 32 + l4 * 8]);
#pragma unroll
        for (int m = 0; m < 4; ++m)
#pragma unroll
            for (int n = 0; n < 4; ++n)
                acc[m][n] = __builtin_amdgcn_mfma_f32_16x16x32_bf16(af[m], bfr[n], acc[m][n], 0, 0, 0);

        __builtin_amdgcn_s_barrier();
        __builtin_amdgcn_sched_barrier(0);
        cs = (cs == 2) ? 0 : cs + 1;
        ps = (ps == 2) ? 0 : ps + 1;
    }
#undef STAGE_TILE

    const int rbase = bm * 128 + wm * 64;
    const int cbase = bn * 128 + wn * 64;
#pragma unroll
    for (int m = 0; m < 4; ++m) {
#pragma unroll
        for (int n = 0; n < 4; ++n) {
            const int c = cbase + n * 16 + l15;
#pragma unroll
            for (int j = 0; j < 4; ++j) {
                const int rr = rbase + m * 16 + l4 * 4 + j;
                if (F32OUT)
                    ((float*)Cout)[(size_t)rr * N + c] = acc[m][n][j] + bias[c];
                else
                    ((u16*)Cout)[(size_t)rr * N + c] = f2bf(acc[m][n][j]);
            }
        }
    }
}

// ---------------- causal flash attention, K/V DOUBLE-BUFFERED (distance 1) ----------------
// grid: 2048 1-D heavy-first. Per kt: stage kt+1 -> buf^1 (8 loads/thread), counted
// vmcnt(8) confirms tile kt's loads, barrier A, compute kt, barrier B. Race-free:
// stage(kt+1) follows barrier B of kt-1 (last reader of buf^1) in program order;
// ds_reads of buf kt retire before barrier B (their MFMA consumers precede it).
// Ps is wave-private (no barrier). LDS 72KB -> 2 blocks/CU.
__global__ __launch_bounds__(256) void attn_kernel(const u16* __restrict__ qk,
                                                   const u16* __restrict__ vt,
                                                   u16* __restrict__ ctx) {
    __shared__ u16 Ks[2 * 64 * 128];   // [buf][kv][dh], chunk c at c ^ (kv&15)
    __shared__ u16 Vs[2 * 128 * 64];   // [buf][dh][kv], chunk c at c ^ (dh&7)
    __shared__ u16 Ps[4 * 16 * 64];    // per-wave [q][kv], chunk c at c ^ (q&7)
    const int tid = threadIdx.x, lane = tid & 63, w = tid >> 6;
    const int l15 = lane & 15, l4 = lane >> 4;
    const int flat = blockIdx.x;
    const int qt = 31 - (flat >> 6);
    const int bh = flat & 63;
    const int b = bh >> 4, h = bh & 15;
    const int qb = qt * 64;

    bf16x8 qf[4];
    {
        const size_t rowQ = (size_t)(b * 2048 + qb + w * 16 + l15) * 4096 + h * 128;
#pragma unroll
        for (int kk = 0; kk < 4; kk++)
            qf[kk] = *reinterpret_cast<const bf16x8*>(&qk[rowQ + kk * 32 + l4 * 8]);
    }

    const int krow_i = tid >> 4, kslot = tid & 15;
    const int vrow_i = tid >> 3, vslot = tid & 7;

#define STAGE_KV(BUF, KT)                                                                \
    {                                                                                    \
        const int kvb_ = (KT) * 64;                                                      \
        _Pragma("unroll") for (int p = 0; p < 4; ++p) {                                  \
            const int rowk = p * 16 + krow_i;                                            \
            const int ck = kslot ^ (rowk & 15);                                          \
            __builtin_amdgcn_global_load_lds(                                            \
                (gbl_void*)(qk + (size_t)(b * 2048 + kvb_ + rowk) * 4096 + 2048 +        \
                            h * 128 + ck * 8),                                           \
                (lds_void*)((char*)Ks + (BUF) * 16384 + p * 4096 + w * 1024), 16, 0, 0); \
        }                                                                                \
        _Pragma("unroll") for (int p = 0; p < 4; ++p) {                                  \
            const int rowv = p * 32 + vrow_i;                                            \
            const int cv = vslot ^ (rowv & 7);                                           \
            __builtin_amdgcn_global_load_lds(                                            \
                (gbl_void*)(vt + (size_t)(h * 128 + rowv) * 8192 + b * 2048 + kvb_ +     \
                            cv * 8),                                                     \
                (lds_void*)((char*)Vs + (BUF) * 16384 + p * 4096 + w * 1024), 16, 0, 0); \
        }                                                                                \
    }

    float m_r[4], l_r[4];
    f32x4 o[8] = {};
#pragma unroll
    for (int j = 0; j < 4; ++j) { m_r[j] = -1e30f; l_r[j] = 0.f; }

    STAGE_KV(0, 0);

    for (int kt = 0; kt <= qt; ++kt) {
        const int buf = kt & 1;
        const int kb16 = buf * 8192;  // u16 offset of this buffer
        if (kt < qt) {
            STAGE_KV(buf ^ 1, kt + 1);
            asm volatile("s_waitcnt vmcnt(8)" ::: "memory");
        } else {
            asm volatile("s_waitcnt vmcnt(0)" ::: "memory");
        }
        __builtin_amdgcn_s_barrier();
        __builtin_amdgcn_sched_barrier(0);

        f32x4 s[4] = {};
#pragma unroll
        for (int cb = 0; cb < 4; ++cb) {
            const int krow = cb * 16 + l15;
#pragma unroll
            for (int kk = 0; kk < 4; ++kk) {
                bf16x8 kf = *reinterpret_cast<const bf16x8*>(
                    &Ks[kb16 + krow * 128 + (((kk * 4 + l4) ^ (krow & 15)) << 3)]);
                s[cb] = __builtin_amdgcn_mfma_f32_16x16x32_bf16(qf[kk], kf, s[cb], 0, 0, 0);
            }
        }
        const float sc = 0.08838834764831845f;  // 1/sqrt(128)
#pragma unroll
        for (int cb = 0; cb < 4; ++cb) s[cb] *= sc;

        if (kt == qt) {
#pragma unroll
            for (int cb = 0; cb < 4; ++cb)
#pragma unroll
                for (int j = 0; j < 4; ++j) {
                    int lr = w * 16 + l4 * 4 + j, lc = cb * 16 + l15;
                    if (lc > lr) s[cb][j] = -1e30f;
                }
        }

#pragma unroll
        for (int j = 0; j < 4; ++j) {
            float tm = fmaxf(fmaxf(s[0][j], s[1][j]), fmaxf(s[2][j], s[3][j]));
#pragma unroll
            for (int msk = 1; msk < 16; msk <<= 1)
                tm = fmaxf(tm, __shfl_xor(tm, msk, 64));
            float mnew = fmaxf(m_r[j], tm);
            float alpha = __expf(m_r[j] - mnew);
            m_r[j] = mnew;
            float rs = 0.f;
#pragma unroll
            for (int cb = 0; cb < 4; ++cb) {
                float p = __expf(s[cb][j] - mnew);
                s[cb][j] = p;
                rs += p;
            }
#pragma unroll
            for (int msk = 1; msk < 16; msk <<= 1)
                rs += __shfl_xor(rs, msk, 64);
            l_r[j] = l_r[j] * alpha + rs;
#pragma unroll
            for (int d = 0; d < 8; ++d) o[d][j] *= alpha;
        }

#pragma unroll
        for (int cb = 0; cb < 4; ++cb)
#pragma unroll
            for (int j = 0; j < 4; ++j) {
                const int rr = l4 * 4 + j;
                const int e = cb * 16 + l15;
                Ps[w * 1024 + rr * 64 + (((e >> 3) ^ (rr & 7)) << 3) + (e & 7)] = f2bf(s[cb][j]);
            }

#pragma unroll
        for (int ks = 0; ks < 2; ++ks) {
            bf16x8 pf = *reinterpret_cast<const bf16x8*>(
                &Ps[w * 1024 + l15 * 64 + (((ks * 4 + l4) ^ (l15 & 7)) << 3)]);
#pragma unroll
            for (int d = 0; d < 8; ++d) {
                const int dr = d * 16 + l15;
                bf16x8 vf = *reinterpret_cast<const bf16x8*>(
                    &Vs[kb16 + dr * 64 + (((ks * 4 + l4) ^ (dr & 7)) << 3)]);
                o[d] = __builtin_amdgcn_mfma_f32_16x16x32_bf16(pf, vf, o[d], 0, 0, 0);
            }
        }
        __builtin_amdgcn_s_barrier();
        __builtin_amdgcn_sched_barrier(0);
    }
#undef STAGE_KV

#pragma unroll
    for (int j = 0; j < 4; ++j) {
        float inv = 1.0f / l_r[j];
        size_t row = (size_t)(b * 2048 + qb + w * 16 + l4 * 4 + j) * 2048 + h * 128;
#pragma unroll
        for (int d = 0; d < 8; ++d)
            ctx[row + d * 16 + l15] = f2bf(o[d][j] * inv);
    }
}

extern "C" void kernel_launch(void* const* d_in, const int* in_sizes, int n_in,
                              void* d_out, int out_size, void* d_ws, size_t ws_size,
                              hipStream_t stream) {
    const float* x  = (const float*)d_in[0];
    const float* Wq = (const float*)d_in[1];
    const float* Wk = (const float*)d_in[2];
    const float* Wv = (const float*)d_in[3];
    const float* Wo = (const float*)d_in[4];
    const float* bo = (const float*)d_in[5];
    float* out = (float*)d_out;

    char* ws = (char*)d_ws;
    u16* xb  = (u16*)(ws);                         // 8192x2048 bf16 (33.5MB); reused as ctx
    u16* wt  = (u16*)(ws + 33554432);              // WqT|WkT|WvT, 3x 2048x2048 bf16 (25.2MB)
    u16* wto = (u16*)(ws + 33554432 + 25165824);   // WoT 2048x2048 bf16 (8.4MB)
    u16* qk  = (u16*)(ws + 67108864);              // 8192x4096 bf16 (67.1MB)
    u16* vtb = (u16*)(ws + 134217728);             // 2048x8192 bf16 V^T (33.5MB)
    u16* wtv = wt + 2 * 2048 * 2048;
    u16* ctxb = xb;

    cvt_bf16_kernel<<<16384, 256, 0, stream>>>(x, xb, 4194304);
    dim3 tb(32, 8), tg(64, 64);
    transpose_w_kernel<<<tg, tb, 0, stream>>>(Wq, wt);
    transpose_w_kernel<<<tg, tb, 0, stream>>>(Wk, wt + 2048 * 2048);
    transpose_w_kernel<<<tg, tb, 0, stream>>>(Wv, wtv);
    transpose_w_kernel<<<tg, tb, 0, stream>>>(Wo, wto);

    // Q|K: [8192][4096] = xb @ [WqT|WkT]^T
    gemm_bt_kernel<false><<<dim3(64, 32), 256, 0, stream>>>(xb, wt, qk, nullptr, 8192, 4096, 2048);
    // V^T: [2048][8192] = WvT @ xb^T
    gemm_bt_kernel<false><<<dim3(16, 64), 256, 0, stream>>>(wtv, xb, vtb, nullptr, 2048, 8192, 2048);
    attn_kernel<<<2048, 256, 0, stream>>>(qk, vtb, ctxb);
    gemm_bt_kernel<true><<<dim3(64, 16), 256, 0, stream>>>(ctxb, wto, out, bo, 8192, 2048, 2048);
}